// Round 1
// 64.881 us; speedup vs baseline: 1.1466x; 1.1466x over previous
//
#include <hip/hip_runtime.h>

// Banded-block sparse attention, B=4, S=4096, D=128, block=64, w=32.
// Masked scores are 0 (not -inf) -> closed-form out-of-band correction.
// fp16 MFMA path, exp2 domain, swapped QK^T, defer-max (THR=8 log2 units).
//
// R1 restructure: split each (b,ib) into 4 KV chunks -> grid 1024 x 256thr,
// 40KB LDS (single-buffered K/V + XOR-swizzled P) -> 4 wg/CU = 4 waves/SIMD
// of decoupled streams (was 1 wg/CU, 2 lockstep waves/SIMD). Partials
// (f16 o + f32 m,l) merged by a 3rd kernel (flash-merge + out-of-band term).

typedef _Float16 f16;
typedef __attribute__((ext_vector_type(8))) _Float16 f16x8;
typedef __attribute__((ext_vector_type(4))) _Float16 f16x4;
typedef __attribute__((ext_vector_type(4))) float f32x4;

#define MFMA16(a, b, c) __builtin_amdgcn_mfma_f32_16x16x32_f16((a), (b), (c), 0, 0, 0)

#define BATCH 4
#define SEQ   4096
#define DIM   128
#define NB    64
#define WBAND 32
#define LOG2E 1.44269504088896f
#define DTHR  8.0f

#define KTILE 16384   // 64 rows x 128 f16, 256B rows, chunk XOR-swizzled
#define VTILE 16384   // 128 d-rows x 64 f16, 128B rows, chunk XOR-swizzled
#define TSTR  72

#define CHUNKS 4
#define PART_STRIDE 16896  // 16384B o (f16 [4][64][8][4] lane-major) + 512B (m,l) f32

__device__ __forceinline__ void gl16(const char* g, char* l) {
  __builtin_amdgcn_global_load_lds(
      (const __attribute__((address_space(1))) void*)g,
      (__attribute__((address_space(3))) void*)l, 16, 0, 0);
}

// ---------------------------------------------------------------------------
__global__ __launch_bounds__(256) void convert_kernel(
    const float* __restrict__ K, const float* __restrict__ V,
    f16* __restrict__ KT, f16* __restrict__ VT, float* __restrict__ BS) {
  __shared__ f16 T[128 * TSTR];
  const int blk = blockIdx.x;
  const int b = blk >> 6, jb = blk & 63;
  const int s0 = jb * 64;
  const int t = threadIdx.x;
  char* ktile = (char*)KT + (size_t)blk * KTILE;
  char* vtile = (char*)VT + (size_t)blk * VTILE;

#pragma unroll
  for (int i = 0; i < 4; ++i) {
    int idx = t + i * 256;
    int row = idx >> 4;
    int c = idx & 15;
    const float* src = K + ((size_t)(b * SEQ + s0 + row)) * DIM + c * 8;
    float4 a = *(const float4*)src;
    float4 d = *(const float4*)(src + 4);
    f16x8 h = {(f16)a.x, (f16)a.y, (f16)a.z, (f16)a.w,
               (f16)d.x, (f16)d.y, (f16)d.z, (f16)d.w};
    *(f16x8*)(ktile + row * 256 + ((c ^ (row & 15)) * 16)) = h;
  }

#pragma unroll
  for (int i = 0; i < 8; ++i) {
    int idx = t + i * 256;
    int row = idx >> 5;
    int c4 = (idx & 31) * 4;
    float4 v = *(const float4*)(V + (size_t)(b * SEQ + s0 + row) * DIM + c4);
    T[(c4 + 0) * TSTR + row] = (f16)v.x;
    T[(c4 + 1) * TSTR + row] = (f16)v.y;
    T[(c4 + 2) * TSTR + row] = (f16)v.z;
    T[(c4 + 3) * TSTR + row] = (f16)v.w;
  }
  __syncthreads();

#pragma unroll
  for (int i = 0; i < 4; ++i) {
    int idx = t + i * 256;
    int d = idx >> 3;
    int c = idx & 7;
    f16x8 val = *(const f16x8*)(T + d * TSTR + c * 8);
    *(f16x8*)(vtile + d * 128 + ((c ^ (d & 7)) * 16)) = val;
  }

  if (t < 128) {
    float s = 0.f;
    for (int k = 0; k < 64; ++k) s += (float)T[t * TSTR + k];
    BS[(b * NB + jb) * DIM + t] = s;
  }
}

// ---------------------------------------------------------------------------
// 40960 B LDS: K tile @0 (16K), V tile @16384 (16K), P @32768 (4 waves x 2K)
__global__ __launch_bounds__(256, 4) void attn_kernel(
    const float* __restrict__ Q, const f16* __restrict__ KT,
    const f16* __restrict__ VT, char* __restrict__ PART) {
  __shared__ __align__(16) char smem[40960];

  const int id = blockIdx.x;
  const int lin = (id & 7) * 128 + (id >> 3);  // XCD-contiguous (b,ib) bands
  const int ck = lin & 3;
  const int ib = (lin >> 2) & 63;
  const int b = lin >> 8;

  const int t = threadIdx.x;
  const int w = t >> 6, l = t & 63, lg = l >> 4, ll = l & 15;

  const int jlo = max(0, ib - WBAND);
  const int jhi = min(NB, ib + WBAND);
  const int n = jhi - jlo;          // 32..64
  const int c = (n + 3) >> 2;       // 8..16
  const int j0 = jlo + ck * c;
  const int nloc = min(c, jhi - j0);  // >= 6 always
  const int q0 = ib * 64;

  // Q fragments (pre-scaled by log2 e). Same per-lane layout serves as the
  // MFMA B operand (col = ll = q row, k = lg*8+e).
  f16x8 qf[4];
  {
    const float* qrow = Q + ((size_t)(b * SEQ + q0 + w * 16 + ll)) * DIM;
#pragma unroll
    for (int ks = 0; ks < 4; ++ks) {
      int d0 = ks * 32 + lg * 8;
      float4 a = *(const float4*)(qrow + d0);
      float4 cc = *(const float4*)(qrow + d0 + 4);
      float vv[8] = {a.x, a.y, a.z, a.w, cc.x, cc.y, cc.z, cc.w};
#pragma unroll
      for (int e = 0; e < 8; ++e) qf[ks][e] = (f16)(vv[e] * LOG2E);
    }
  }

  float m2 = 0.f;    // running max (log2 domain); 0 = masked-entry max
  float ell = 0.f;   // per-lane partial row sum (combined across lg at end)
  f32x4 o[8];
#pragma unroll
  for (int nt = 0; nt < 8; ++nt) o[nt] = (f32x4){0.f, 0.f, 0.f, 0.f};

  f16* Pw = (f16*)(smem + 32768 + w * 2048);  // 16 rows x 64 f16, XOR-swizzled

  auto stage = [&](int jb) {
    const char* kg = (const char*)KT + ((size_t)(b * NB + jb)) * KTILE + t * 16;
    const char* vg = (const char*)VT + ((size_t)(b * NB + jb)) * VTILE + t * 16;
#pragma unroll
    for (int i = 0; i < 4; ++i) gl16(kg + i * 4096, smem + t * 16 + i * 4096);
#pragma unroll
    for (int i = 0; i < 4; ++i) gl16(vg + i * 4096, smem + 16384 + t * 16 + i * 4096);
  };

  stage(j0);
  __syncthreads();  // compiler-inserted vmcnt(0) drain -> tile 0 ready

  for (int tt = 0; tt < nloc; ++tt) {
    const char* kb = smem;
    const char* vb = smem + 16384;

    // S^T = K * Q^T : sacc[jt][r] = S[q=ll][key = jt*16 + lg*4 + r]
    f32x4 sacc[4];
#pragma unroll
    for (int jt = 0; jt < 4; ++jt) sacc[jt] = (f32x4){0.f, 0.f, 0.f, 0.f};
    __builtin_amdgcn_s_setprio(1);
#pragma unroll
    for (int ks = 0; ks < 4; ++ks) {
#pragma unroll
      for (int jt = 0; jt < 4; ++jt) {
        int row = jt * 16 + ll;
        f16x8 kf = *(const f16x8*)(kb + row * 256 + (((ks * 4 + lg) ^ ll) * 16));
        sacc[jt] = MFMA16(kf, qf[ks], sacc[jt]);
      }
    }
    __builtin_amdgcn_s_setprio(0);

    // lane-local row max (16 values) + 2 cross-lane combines
    float vm = sacc[0][0];
#pragma unroll
    for (int jt = 0; jt < 4; ++jt)
#pragma unroll
      for (int r = 0; r < 4; ++r) vm = fmaxf(vm, sacc[jt][r]);
    vm = fmaxf(vm, __shfl_xor(vm, 16));
    vm = fmaxf(vm, __shfl_xor(vm, 32));

    // defer-max: rescale only when the max grew by > DTHR
    if (__any(vm - m2 > DTHR)) {
      float nm = fmaxf(m2, vm);
      float scl = __builtin_amdgcn_exp2f(m2 - nm);
      m2 = nm;
      ell *= scl;
      float sb[4];
#pragma unroll
      for (int r = 0; r < 4; ++r) sb[r] = __shfl(scl, lg * 4 + r);
#pragma unroll
      for (int nt = 0; nt < 8; ++nt)
#pragma unroll
        for (int r = 0; r < 4; ++r) o[nt][r] *= sb[r];
    }

    // P = 2^(S - m2); pack 4 consecutive keys -> one ds_write_b64.
    // P row = 64 f16 (128B); XOR-swizzle byte^=((ll&7)<<4) -> 2-way banks.
    float rsum = 0.f;
#pragma unroll
    for (int jt = 0; jt < 4; ++jt) {
      f16x4 pk;
#pragma unroll
      for (int r = 0; r < 4; ++r) {
        float p = __builtin_amdgcn_exp2f(sacc[jt][r] - m2);
        rsum += p;
        pk[r] = (f16)p;
      }
      *(f16x4*)(Pw + ll * 64 + ((jt * 16 + lg * 4) ^ ((ll & 7) << 3))) = pk;
    }
    ell += rsum;  // lane-local; cross-lane combine deferred to epilogue

    // PV: A = P (row = ll = q, k contiguous), B = VT fragments
    __builtin_amdgcn_s_setprio(1);
#pragma unroll
    for (int ks2 = 0; ks2 < 2; ++ks2) {
      f16x8 pa = *(const f16x8*)(Pw + ll * 64 + ((ks2 * 32 + lg * 8) ^ ((ll & 7) << 3)));
#pragma unroll
      for (int nt = 0; nt < 8; ++nt) {
        int d = nt * 16 + ll;
        f16x8 vbf = *(const f16x8*)(vb + d * 128 + ((((ks2 * 4 + lg) ^ (ll & 7)) * 16)));
        o[nt] = MFMA16(pa, vbf, o[nt]);
      }
    }
    __builtin_amdgcn_s_setprio(0);

    __syncthreads();                       // all waves done reading K/V
    if (tt + 1 < nloc) stage(j0 + tt + 1); // refill single buffer
    __syncthreads();                       // vmcnt(0) drain -> next tile ready
  }

  // finalize per-row sum across the 4 lg lanes (was 2 shfls per tile)
  ell += __shfl_xor(ell, 16);
  ell += __shfl_xor(ell, 32);

  // partial store: o as f16, lane-major layout mirrored by merge_kernel
  char* pb = PART + ((size_t)((b * NB + ib) * CHUNKS + ck)) * PART_STRIDE;
  f16* oc = (f16*)(pb + (w * 64 + l) * 64);
#pragma unroll
  for (int g = 0; g < 4; ++g) {
    f16x8 hh;
#pragma unroll
    for (int r = 0; r < 4; ++r) {
      hh[r] = (f16)o[g * 2][r];
      hh[4 + r] = (f16)o[g * 2 + 1][r];
    }
    *(f16x8*)(oc + g * 8) = hh;
  }
  if (lg == 0) {
    *(float2*)(pb + 16384 + (w * 16 + ll) * 8) = make_float2(m2, ell);
  }
}

// ---------------------------------------------------------------------------
// Flash-merge of 4 chunk partials + closed-form out-of-band correction.
__global__ __launch_bounds__(256) void merge_kernel(
    const char* __restrict__ PART, const float* __restrict__ BS,
    float* __restrict__ Out) {
  __shared__ float VoutS[DIM];
  __shared__ float mlS[CHUNKS][64][2];

  const int id = blockIdx.x;
  const int lin = (id & 7) * 32 + (id >> 3);  // match attn XCD mapping
  const int b = lin >> 6, ib = lin & 63;
  const int t = threadIdx.x;
  const int w = t >> 6, l = t & 63, lg = l >> 4, ll = l & 15;

  const int jlo = max(0, ib - WBAND);
  const int jhi = min(NB, ib + WBAND);
  const int n = jhi - jlo;
  const float cnt_out = (float)(SEQ - n * 64);

  if (t < DIM) {
    float s = 0.f;
    for (int j = 0; j < jlo; ++j) s += BS[(b * NB + j) * DIM + t];
    for (int j = jhi; j < NB; ++j) s += BS[(b * NB + j) * DIM + t];
    VoutS[t] = s;
  }
  const char* pbase = PART + (size_t)((b * NB + ib) * CHUNKS) * PART_STRIDE;
  {
    int k = t >> 6, row = t & 63;
    *(float2*)&mlS[k][row][0] =
        *(const float2*)(pbase + (size_t)k * PART_STRIDE + 16384 + row * 8);
  }
  __syncthreads();

  float aw[4][CHUNKS], en[4], inv[4];
#pragma unroll
  for (int r = 0; r < 4; ++r) {
    int row = w * 16 + lg * 4 + r;
    float M = mlS[0][row][0];
#pragma unroll
    for (int k = 1; k < CHUNKS; ++k) M = fmaxf(M, mlS[k][row][0]);
    en[r] = __builtin_amdgcn_exp2f(-M);
    float den = cnt_out * en[r];
#pragma unroll
    for (int k = 0; k < CHUNKS; ++k) {
      aw[r][k] = __builtin_amdgcn_exp2f(mlS[k][row][0] - M);
      den += aw[r][k] * mlS[k][row][1];
    }
    inv[r] = 1.f / den;
  }

  float acc[8][4];
#pragma unroll
  for (int nt = 0; nt < 8; ++nt)
#pragma unroll
    for (int r = 0; r < 4; ++r) acc[nt][r] = 0.f;

#pragma unroll
  for (int k = 0; k < CHUNKS; ++k) {
    const f16* oc = (const f16*)(pbase + (size_t)k * PART_STRIDE + (w * 64 + l) * 64);
#pragma unroll
    for (int g = 0; g < 4; ++g) {
      f16x8 h = *(const f16x8*)(oc + g * 8);
#pragma unroll
      for (int r = 0; r < 4; ++r) {
        acc[g * 2][r] += aw[r][k] * (float)h[r];
        acc[g * 2 + 1][r] += aw[r][k] * (float)h[4 + r];
      }
    }
  }

  const int q0 = ib * 64;
#pragma unroll
  for (int nt = 0; nt < 8; ++nt) {
    int col = nt * 16 + ll;
    float vout = VoutS[col];
#pragma unroll
    for (int r = 0; r < 4; ++r) {
      int row = w * 16 + lg * 4 + r;
      Out[((size_t)(b * SEQ + q0 + row)) * DIM + col] =
          (acc[nt][r] + en[r] * vout) * inv[r];
    }
  }
}

// ---------------------------------------------------------------------------
extern "C" void kernel_launch(void* const* d_in, const int* in_sizes, int n_in,
                              void* d_out, int out_size, void* d_ws, size_t ws_size,
                              hipStream_t stream) {
  const float* Q = (const float*)d_in[0];
  const float* K = (const float*)d_in[1];
  const float* V = (const float*)d_in[2];
  float* Out = (float*)d_out;

  char* ws = (char*)d_ws;
  f16* KTg = (f16*)ws;                              // 4 MB
  f16* VTg = (f16*)(ws + (size_t)BATCH * NB * KTILE);  // +4 MB
  float* BS = (float*)(ws + 2 * (size_t)BATCH * NB * KTILE);  // +128 KB
  char* PART = ws + 2 * (size_t)BATCH * NB * KTILE + (size_t)BATCH * NB * DIM * 4;  // 17.3 MB

  convert_kernel<<<dim3(BATCH * NB), 256, 0, stream>>>(K, V, KTg, VTg, BS);
  attn_kernel<<<dim3(BATCH * NB * CHUNKS), 256, 0, stream>>>(Q, KTg, VTg, PART);
  merge_kernel<<<dim3(BATCH * NB), 256, 0, stream>>>(PART, BS, Out);
}